// Round 2
// baseline (375.344 us; speedup 1.0000x reference)
//
#include <hip/hip_runtime.h>
#include <math.h>

typedef __attribute__((ext_vector_type(8))) short bf16x8;
typedef __attribute__((ext_vector_type(4))) short bf16x4;
typedef __attribute__((ext_vector_type(4))) float f32x4;

#define DEV static __device__ __forceinline__

DEV unsigned short f2bf(float f) {
  unsigned int u = __float_as_uint(f);
  u += 0x7FFFu + ((u >> 16) & 1u);   // RNE, inputs finite
  return (unsigned short)(u >> 16);
}
DEV float bf2f(unsigned short h) { return __uint_as_float(((unsigned int)h) << 16); }
DEV float wsum(float v) { for (int o = 32; o; o >>= 1) v += __shfl_xor(v, o); return v; }
DEV float wmaxr(float v) { for (int o = 32; o; o >>= 1) v = fmaxf(v, __shfl_xor(v, o)); return v; }

// ---------- weight-quant scale: per-row |w| sums (deterministic 2-stage) ----------
__global__ __launch_bounds__(256) void wred_k(const float* __restrict__ qw,
                                              const float* __restrict__ ow,
                                              float* __restrict__ rowsum) {
  int row = blockIdx.x;  // 0..3071 -> qkv_w, 3072..4095 -> out_w
  const float* p = (row < 3072) ? (qw + (size_t)row * 1024)
                                : (ow + (size_t)(row - 3072) * 1024);
  float s = 0.f;
  for (int i = threadIdx.x; i < 1024; i += 256) s += fabsf(p[i]);
  s = wsum(s);
  __shared__ float sh[4];
  if ((threadIdx.x & 63) == 0) sh[threadIdx.x >> 6] = s;
  __syncthreads();
  if (threadIdx.x == 0) rowsum[row] = sh[0] + sh[1] + sh[2] + sh[3];
}

__global__ __launch_bounds__(256) void finalize_k(const float* __restrict__ rowsum,
                                                  float* __restrict__ scales) {
  float s1 = 0.f, s2 = 0.f;
  for (int i = threadIdx.x; i < 3072; i += 256) s1 += rowsum[i];
  for (int i = threadIdx.x; i < 1024; i += 256) s2 += rowsum[3072 + i];
  s1 = wsum(s1); s2 = wsum(s2);
  __shared__ float sh1[4], sh2[4];
  if ((threadIdx.x & 63) == 0) { sh1[threadIdx.x >> 6] = s1; sh2[threadIdx.x >> 6] = s2; }
  __syncthreads();
  if (threadIdx.x == 0) {
    float m1 = fmaxf((sh1[0] + sh1[1] + sh1[2] + sh1[3]) / (3072.f * 1024.f), 1e-5f);
    float m2 = fmaxf((sh2[0] + sh2[1] + sh2[2] + sh2[3]) / (1024.f * 1024.f), 1e-5f);
    scales[0] = m1; scales[1] = 1.f / m1;   // clipped mean, 1/mean
    scales[2] = m2; scales[3] = 1.f / m2;
  }
}

// ternary-quantize both weight matrices -> bf16
// total elements: 3072*1024 + 1024*1024 = 4194304 = 4096 blocks * 256 thr * 4
__global__ __launch_bounds__(256) void wquant_k(const float* __restrict__ qw,
                                                const float* __restrict__ ow,
                                                const float* __restrict__ scales,
                                                unsigned short* __restrict__ Wq,
                                                unsigned short* __restrict__ Wo) {
  int i0 = (blockIdx.x * 256 + threadIdx.x) * 4;
  for (int j = 0; j < 4; j++) {
    int idx = i0 + j;
    if (idx < 3072 * 1024) {
      float v = fminf(fmaxf(rintf(qw[idx] * scales[1]), -1.f), 1.f) * scales[0];
      Wq[idx] = f2bf(v);
    } else if (idx < 3072 * 1024 + 1024 * 1024) {
      int k = idx - 3072 * 1024;
      float v = fminf(fmaxf(rintf(ow[k] * scales[3]), -1.f), 1.f) * scales[2];
      Wo[k] = f2bf(v);
    }
  }
}

// ---------- ada = 1 + cond @ norm_w^T : one wave per output ----------
__global__ __launch_bounds__(256) void ada_k(const float* __restrict__ cond,
                                             const float* __restrict__ nw,
                                             float* __restrict__ ada) {
  int j = blockIdx.x * 4 + (threadIdx.x >> 6);
  int b = blockIdx.y;
  int l = threadIdx.x & 63;
  const float* cp = cond + b * 1024;
  const float* wp = nw + (size_t)j * 1024;
  float s = 0.f;
  for (int c = l; c < 1024; c += 64) s += cp[c] * wp[c];
  s = wsum(s);
  if (l == 0) ada[b * 1024 + j] = 1.f + s;
}

// ---------- RMSNorm(ada) + act_quant -> bf16 activations ----------
__global__ __launch_bounds__(256) void rmsq_k(const float* __restrict__ x,
                                              const float* __restrict__ ada,
                                              unsigned short* __restrict__ Aq) {
  int row = blockIdx.x;          // b*2048 + t
  int b = row >> 11;
  const float* xr = x + (size_t)row * 1024;
  const float* ar = ada + b * 1024;
  float v[4]; float ss = 0.f;
  for (int i = 0; i < 4; i++) { v[i] = xr[threadIdx.x + i * 256]; ss += v[i] * v[i]; }
  ss = wsum(ss);
  __shared__ float sh[4], sh2[4];
  if ((threadIdx.x & 63) == 0) sh[threadIdx.x >> 6] = ss;
  __syncthreads();
  float inv = rsqrtf((sh[0] + sh[1] + sh[2] + sh[3]) * (1.f / 1024.f) + 1e-6f);
  float xn[4]; float mx = 0.f;
  for (int i = 0; i < 4; i++) {
    xn[i] = v[i] * ar[threadIdx.x + i * 256] * inv;
    mx = fmaxf(mx, fabsf(xn[i]));
  }
  mx = wmaxr(mx);
  if ((threadIdx.x & 63) == 0) sh2[threadIdx.x >> 6] = mx;
  __syncthreads();
  float rmax = fmaxf(fmaxf(sh2[0], sh2[1]), fmaxf(sh2[2], sh2[3]));
  float s = 127.f / fmaxf(rmax, 1e-5f);
  float is = 1.f / s;
  unsigned short* dst = Aq + (size_t)row * 1024;
  for (int i = 0; i < 4; i++) {
    float q = fminf(fmaxf(rintf(xn[i] * s), -128.f), 127.f) * is;
    dst[threadIdx.x + i * 256] = f2bf(q);
  }
}

// ---------- act_quant of attention output ----------
__global__ __launch_bounds__(256) void oquant_k(const float* __restrict__ of,
                                                unsigned short* __restrict__ Oq) {
  int row = blockIdx.x;
  const float* xr = of + (size_t)row * 1024;
  float v[4]; float mx = 0.f;
  for (int i = 0; i < 4; i++) { v[i] = xr[threadIdx.x + i * 256]; mx = fmaxf(mx, fabsf(v[i])); }
  mx = wmaxr(mx);
  __shared__ float sh[4];
  if ((threadIdx.x & 63) == 0) sh[threadIdx.x >> 6] = mx;
  __syncthreads();
  float rmax = fmaxf(fmaxf(sh[0], sh[1]), fmaxf(sh[2], sh[3]));
  float s = 127.f / fmaxf(rmax, 1e-5f);
  float is = 1.f / s;
  unsigned short* dst = Oq + (size_t)row * 1024;
  for (int i = 0; i < 4; i++)
    dst[threadIdx.x + i * 256] = f2bf(fminf(fmaxf(rintf(v[i] * s), -128.f), 127.f) * is);
}

// ---------- C[M][N] = A[M][K] * B[N][K]^T, bf16 MFMA, 64x64 tile ----------
__global__ __launch_bounds__(256) void gemm_bt(const unsigned short* __restrict__ A,
                                               const unsigned short* __restrict__ Bw,
                                               int N, int K, int mode,
                                               const float* __restrict__ skip,
                                               float* __restrict__ outF,
                                               unsigned short* __restrict__ outB) {
  __shared__ unsigned short As[64][40];  // +8 pad: 80B rows, 16B aligned, conflict-free
  __shared__ unsigned short Bs[64][40];
  int tm = blockIdx.x * 64, tn = blockIdx.y * 64;
  int tid = threadIdx.x;
  int l = tid & 63, w = tid >> 6;
  int q = l & 15, g = l >> 4;
  f32x4 acc[4];
  f32x4 zero = {0.f, 0.f, 0.f, 0.f};
  for (int i = 0; i < 4; i++) acc[i] = zero;
  int sr = tid >> 2, sc = (tid & 3) * 8;
  for (int k0 = 0; k0 < K; k0 += 32) {
    *(bf16x8*)&As[sr][sc] = *(const bf16x8*)(A + (size_t)(tm + sr) * K + k0 + sc);
    *(bf16x8*)&Bs[sr][sc] = *(const bf16x8*)(Bw + (size_t)(tn + sr) * K + k0 + sc);
    __syncthreads();
    bf16x8 af = *(const bf16x8*)&As[w * 16 + q][g * 8];
    for (int nb = 0; nb < 4; nb++) {
      bf16x8 bfg = *(const bf16x8*)&Bs[nb * 16 + q][g * 8];
      acc[nb] = __builtin_amdgcn_mfma_f32_16x16x32_bf16(af, bfg, acc[nb], 0, 0, 0);
    }
    __syncthreads();
  }
  for (int nb = 0; nb < 4; nb++) {
    int col = tn + nb * 16 + q;
    for (int r = 0; r < 4; r++) {
      int row = tm + w * 16 + g * 4 + r;
      float vv = acc[nb][r];
      if (mode == 0) outB[(size_t)row * N + col] = f2bf(vv);
      else { size_t idx = (size_t)row * N + col; outF[idx] = vv + skip[idx]; }
    }
  }
}

// ---------- qk-norm + RoPE: one wave per (b,t,h), lane = head-dim ----------
__global__ __launch_bounds__(256) void rope_k(const unsigned short* __restrict__ qkv,
                                              const float* __restrict__ pos,
                                              const float* __restrict__ scale,
                                              const float* __restrict__ freqs,
                                              unsigned short* __restrict__ Qo,
                                              unsigned short* __restrict__ Ko) {
  int tid = threadIdx.x;
  int w = tid >> 6, l = tid & 63;
  int gw = blockIdx.x * 4 + w;            // b*32768 + t*16 + h
  int h = gw & 15, t = (gw >> 4) & 2047, b = gw >> 15;
  const unsigned short* base = qkv + ((size_t)(b * 2048 + t)) * 3072 + h * 64 + l;
  float qv = bf2f(base[0]);
  float kv = bf2f(base[1024]);
  float sq = qv * qv, sk = kv * kv;
  for (int o = 32; o; o >>= 1) { sq += __shfl_xor(sq, o); sk += __shfl_xor(sk, o); }
  float ssc = sqrtf(scale[h]);
  float fq = ssc * rsqrtf(sq + 1e-6f);
  float fk = ssc * rsqrtf(sk + 1e-6f);
  float qn = qv * fq, kn = kv * fk;
  int e = l;
  int idx24 = (e < 24) ? e : e - 24;
  int partner = (e < 24) ? e + 24 : ((e < 48) ? e - 24 : e);
  float qo = __shfl(qn, partner), ko = __shfl(kn, partner);
  float qr = qn, kr = kn;
  if (e < 48) {
    int a = idx24 >> 3, f = idx24 & 7;
    float th = pos[((size_t)(b * 2048 + t)) * 3 + a] * freqs[h * 8 + f];
    float sn, cs; sincosf(th, &sn, &cs);
    if (e < 24) { qr = qn * cs - qo * sn; kr = kn * cs - ko * sn; }
    else        { qr = qn * cs + qo * sn; kr = kn * cs + ko * sn; }
  }
  size_t oi = ((size_t)((b * 16 + h) * 2048 + t)) * 64 + e;
  Qo[oi] = f2bf(qr);
  Ko[oi] = f2bf(kr);
}

// ---------- V transpose: VT[b][h][e][t] ----------
__global__ __launch_bounds__(256) void vtrans_k(const unsigned short* __restrict__ qkv,
                                                unsigned short* __restrict__ VT) {
  __shared__ unsigned short tile[64][72];
  int tt = blockIdx.x, bh = blockIdx.y;
  int b = bh >> 4, h = bh & 15;
  int tid = threadIdx.x;
  for (int ro = 0; ro < 2; ro++) {
    int r = ro * 32 + (tid >> 3);
    int c = (tid & 7) * 8;
    *(bf16x8*)&tile[r][c] =
        *(const bf16x8*)(qkv + ((size_t)(b * 2048 + tt * 64 + r)) * 3072 + 2048 + h * 64 + c);
  }
  __syncthreads();
  int e = tid >> 2;
  int tc = (tid & 3) * 16;
  bf16x8 o0, o1;
  for (int i = 0; i < 8; i++) { o0[i] = (short)tile[tc + i][e]; o1[i] = (short)tile[tc + 8 + i][e]; }
  unsigned short* dst = VT + ((size_t)(bh * 64 + e)) * 2048 + tt * 64 + tc;
  *(bf16x8*)dst = o0;
  *(bf16x8*)(dst + 8) = o1;
}

// ---------- flash attention: 1 wave = 16 Q rows, swapped QK^T ----------
__global__ __launch_bounds__(256) void attn_k(const unsigned short* __restrict__ Q,
                                              const unsigned short* __restrict__ K,
                                              const unsigned short* __restrict__ VT,
                                              float* __restrict__ O) {
  __shared__ unsigned short pQ[4][16][40];   // wave-private P^T tile [q][ktok], padded
  int tid = threadIdx.x;
  int w = tid >> 6, l = tid & 63;
  int q = l & 15, g = l >> 4;
  int gw = blockIdx.x * 4 + w;
  int qt = gw & 127, bh = gw >> 7;
  const unsigned short* Qp = Q + ((size_t)bh * 2048 + qt * 16 + q) * 64 + g * 8;
  bf16x8 qa0 = *(const bf16x8*)Qp;          // B-frag: col=q(lane&15), k=g*8..+8
  bf16x8 qa1 = *(const bf16x8*)(Qp + 32);
  const unsigned short* Kb = K + (size_t)bh * 2048 * 64;
  const unsigned short* Vb = VT + (size_t)bh * 64 * 2048;
  f32x4 acc[4];
  f32x4 zero = {0.f, 0.f, 0.f, 0.f};
  for (int i = 0; i < 4; i++) acc[i] = zero;
  float m = -INFINITY, sum = 0.f;
  for (int kt = 0; kt < 2048; kt += 32) {
    // S^T = K . Q^T  (A rows = k-tokens: lane&15 is ktok here)
    const unsigned short* Kp = Kb + (size_t)(kt + q) * 64 + g * 8;
    bf16x8 k0a = *(const bf16x8*)Kp;
    bf16x8 k0b = *(const bf16x8*)(Kp + 32);
    bf16x8 k1a = *(const bf16x8*)(Kp + 16 * 64);
    bf16x8 k1b = *(const bf16x8*)(Kp + 16 * 64 + 32);
    f32x4 s0 = zero, s1 = zero;
    s0 = __builtin_amdgcn_mfma_f32_16x16x32_bf16(k0a, qa0, s0, 0, 0, 0);
    s0 = __builtin_amdgcn_mfma_f32_16x16x32_bf16(k0b, qa1, s0, 0, 0, 0);
    s1 = __builtin_amdgcn_mfma_f32_16x16x32_bf16(k1a, qa0, s1, 0, 0, 0);
    s1 = __builtin_amdgcn_mfma_f32_16x16x32_bf16(k1b, qa1, s1, 0, 0, 0);
    // online softmax: each lane holds 8 scores for its q; reduce across g-groups
    float tm = fmaxf(fmaxf(fmaxf(s0[0], s0[1]), fmaxf(s0[2], s0[3])),
                     fmaxf(fmaxf(s1[0], s1[1]), fmaxf(s1[2], s1[3])));
    tm = fmaxf(tm, __shfl_xor(tm, 16));
    tm = fmaxf(tm, __shfl_xor(tm, 32));
    float mn = fmaxf(m, tm);
    float alpha = __expf(m - mn);           // first iter: exp(-inf)=0
    float p0[4], p1[4], ts = 0.f;
    for (int r = 0; r < 4; r++) {
      p0[r] = __expf(s0[r] - mn); p1[r] = __expf(s1[r] - mn);
      ts += p0[r] + p1[r];
    }
    ts += __shfl_xor(ts, 16);
    ts += __shfl_xor(ts, 32);
    sum = sum * alpha + ts;
    m = mn;
    for (int i = 0; i < 4; i++)
      for (int r = 0; r < 4; r++) acc[i][r] *= alpha;
    // P^T -> LDS (wave-private transpose staging)
    bf16x4 u0, u1;
    for (int r = 0; r < 4; r++) { u0[r] = (short)f2bf(p0[r]); u1[r] = (short)f2bf(p1[r]); }
    *(bf16x4*)&pQ[w][q][g * 4] = u0;        // ktok 0..15
    *(bf16x4*)&pQ[w][q][16 + g * 4] = u1;   // ktok 16..31
    __builtin_amdgcn_sched_barrier(0);
    bf16x8 pb = *(const bf16x8*)&pQ[w][q][g * 8];   // B-frag: col=q, k=ktok g*8..+8
    // O^T += V^T . P^T : A-frag rows = e (lane&15), k = ktok
    const unsigned short* Vp = Vb + (size_t)q * 2048 + kt + g * 8;
    bf16x8 v0 = *(const bf16x8*)Vp;
    bf16x8 v1 = *(const bf16x8*)(Vp + 16 * 2048);
    bf16x8 v2 = *(const bf16x8*)(Vp + 32 * 2048);
    bf16x8 v3 = *(const bf16x8*)(Vp + 48 * 2048);
    acc[0] = __builtin_amdgcn_mfma_f32_16x16x32_bf16(v0, pb, acc[0], 0, 0, 0);
    acc[1] = __builtin_amdgcn_mfma_f32_16x16x32_bf16(v1, pb, acc[1], 0, 0, 0);
    acc[2] = __builtin_amdgcn_mfma_f32_16x16x32_bf16(v2, pb, acc[2], 0, 0, 0);
    acc[3] = __builtin_amdgcn_mfma_f32_16x16x32_bf16(v3, pb, acc[3], 0, 0, 0);
  }
  float is = 1.f / sum;
  int b = bh >> 4, h = bh & 15;
  float* Op = O + ((size_t)(b * 2048 + qt * 16 + q)) * 1024 + h * 64 + g * 4;
  for (int eb = 0; eb < 4; eb++) {
    f32x4 vvv;
    for (int r = 0; r < 4; r++) vvv[r] = acc[eb][r] * is;
    *(f32x4*)(Op + eb * 16) = vvv;
  }
}

extern "C" void kernel_launch(void* const* d_in, const int* in_sizes, int n_in,
                              void* d_out, int out_size, void* d_ws, size_t ws_size,
                              hipStream_t stream) {
  const float* x      = (const float*)d_in[0];   // (2,2048,1024) flat
  const float* pos    = (const float*)d_in[1];   // (2,2048,3)
  const float* cond   = (const float*)d_in[2];   // (2,1024)
  const float* norm_w = (const float*)d_in[3];   // (1024,1024)
  const float* qkv_w  = (const float*)d_in[4];   // (3072,1024)
  const float* out_w  = (const float*)d_in[5];   // (1024,1024)
  const float* scale  = (const float*)d_in[6];   // (16,)
  const float* freqs  = (const float*)d_in[7];   // (16,8)
  float* out = (float*)d_out;
  char* ws = (char*)d_ws;

  // ws layout (bytes), with reuse; total ~56 MB
  const size_t o_ada    = 0;                         // 8 KB
  const size_t o_rowsum = 8192;                      // 16 KB
  const size_t o_scales = 24576;                     // 256 B
  const size_t o_Wq     = 24832;                     // 6 MB
  const size_t o_Wo     = o_Wq + 3072ull*1024*2;     // 2 MB
  const size_t o_Aq     = o_Wo + 1024ull*1024*2;     // 8 MB (reused as Q)
  const size_t o_qkv    = o_Aq + 4096ull*1024*2;     // 24 MB (first 16 MB reused as o_f32)
  const size_t o_K      = o_qkv + 4096ull*3072*2;    // 8 MB (reused as Oq)
  const size_t o_VT     = o_K + 2ull*16*2048*64*2;   // 8 MB

  float* ada            = (float*)(ws + o_ada);
  float* rowsum         = (float*)(ws + o_rowsum);
  float* scales         = (float*)(ws + o_scales);
  unsigned short* Wq    = (unsigned short*)(ws + o_Wq);
  unsigned short* Wo    = (unsigned short*)(ws + o_Wo);
  unsigned short* Aq    = (unsigned short*)(ws + o_Aq);
  unsigned short* Qb    = Aq;                        // reuse after GEMM1
  unsigned short* qkv   = (unsigned short*)(ws + o_qkv);
  float* of             = (float*)(ws + o_qkv);      // reuse after rope/vtrans
  unsigned short* Kb    = (unsigned short*)(ws + o_K);
  unsigned short* Oq    = Kb;                        // reuse after attention
  unsigned short* VT    = (unsigned short*)(ws + o_VT);

  wred_k<<<4096, 256, 0, stream>>>(qkv_w, out_w, rowsum);
  finalize_k<<<1, 256, 0, stream>>>(rowsum, scales);
  wquant_k<<<4096, 256, 0, stream>>>(qkv_w, out_w, scales, Wq, Wo);
  ada_k<<<dim3(256, 2), 256, 0, stream>>>(cond, norm_w, ada);
  rmsq_k<<<4096, 256, 0, stream>>>(x, ada, Aq);
  gemm_bt<<<dim3(64, 48), 256, 0, stream>>>(Aq, Wq, 3072, 1024, 0, nullptr, nullptr, qkv);
  rope_k<<<16384, 256, 0, stream>>>(qkv, pos, scale, freqs, Qb, Kb);
  vtrans_k<<<dim3(32, 32), 256, 0, stream>>>(qkv, VT);
  attn_k<<<1024, 256, 0, stream>>>(Qb, Kb, VT, of);
  oquant_k<<<4096, 256, 0, stream>>>(of, Oq);
  gemm_bt<<<dim3(64, 16), 256, 0, stream>>>(Oq, Wo, 1024, 1024, 1, x, out, nullptr);
}

// Round 3
// 223.223 us; speedup vs baseline: 1.6815x; 1.6815x over previous
//
#include <hip/hip_runtime.h>
#include <math.h>

typedef __attribute__((ext_vector_type(8))) short bf16x8;
typedef __attribute__((ext_vector_type(4))) short bf16x4;
typedef __attribute__((ext_vector_type(4))) float f32x4;

#define DEV static __device__ __forceinline__

DEV unsigned short f2bf(float f) {
  unsigned int u = __float_as_uint(f);
  u += 0x7FFFu + ((u >> 16) & 1u);   // RNE, inputs finite
  return (unsigned short)(u >> 16);
}
DEV float bf2f(unsigned short h) { return __uint_as_float(((unsigned int)h) << 16); }
DEV float wsum(float v) { for (int o = 32; o; o >>= 1) v += __shfl_xor(v, o); return v; }
DEV float wmaxr(float v) { for (int o = 32; o; o >>= 1) v = fmaxf(v, __shfl_xor(v, o)); return v; }

// ---------- weight-quant scale: per-row |w| sums (deterministic 2-stage) ----------
__global__ __launch_bounds__(256) void wred_k(const float* __restrict__ qw,
                                              const float* __restrict__ ow,
                                              float* __restrict__ rowsum) {
  int row = blockIdx.x;  // 0..3071 -> qkv_w, 3072..4095 -> out_w
  const float* p = (row < 3072) ? (qw + (size_t)row * 1024)
                                : (ow + (size_t)(row - 3072) * 1024);
  float s = 0.f;
  for (int i = threadIdx.x; i < 1024; i += 256) s += fabsf(p[i]);
  s = wsum(s);
  __shared__ float sh[4];
  if ((threadIdx.x & 63) == 0) sh[threadIdx.x >> 6] = s;
  __syncthreads();
  if (threadIdx.x == 0) rowsum[row] = sh[0] + sh[1] + sh[2] + sh[3];
}

__global__ __launch_bounds__(256) void finalize_k(const float* __restrict__ rowsum,
                                                  float* __restrict__ scales) {
  float s1 = 0.f, s2 = 0.f;
  for (int i = threadIdx.x; i < 3072; i += 256) s1 += rowsum[i];
  for (int i = threadIdx.x; i < 1024; i += 256) s2 += rowsum[3072 + i];
  s1 = wsum(s1); s2 = wsum(s2);
  __shared__ float sh1[4], sh2[4];
  if ((threadIdx.x & 63) == 0) { sh1[threadIdx.x >> 6] = s1; sh2[threadIdx.x >> 6] = s2; }
  __syncthreads();
  if (threadIdx.x == 0) {
    float m1 = fmaxf((sh1[0] + sh1[1] + sh1[2] + sh1[3]) / (3072.f * 1024.f), 1e-5f);
    float m2 = fmaxf((sh2[0] + sh2[1] + sh2[2] + sh2[3]) / (1024.f * 1024.f), 1e-5f);
    scales[0] = m1; scales[1] = 1.f / m1;   // clipped mean, 1/mean
    scales[2] = m2; scales[3] = 1.f / m2;
  }
}

// ternary-quantize both weight matrices -> bf16
__global__ __launch_bounds__(256) void wquant_k(const float* __restrict__ qw,
                                                const float* __restrict__ ow,
                                                const float* __restrict__ scales,
                                                unsigned short* __restrict__ Wq,
                                                unsigned short* __restrict__ Wo) {
  int i0 = (blockIdx.x * 256 + threadIdx.x) * 4;
  for (int j = 0; j < 4; j++) {
    int idx = i0 + j;
    if (idx < 3072 * 1024) {
      float v = fminf(fmaxf(rintf(qw[idx] * scales[1]), -1.f), 1.f) * scales[0];
      Wq[idx] = f2bf(v);
    } else if (idx < 3072 * 1024 + 1024 * 1024) {
      int k = idx - 3072 * 1024;
      float v = fminf(fmaxf(rintf(ow[k] * scales[3]), -1.f), 1.f) * scales[2];
      Wo[k] = f2bf(v);
    }
  }
}

// ---------- ada = 1 + cond @ norm_w^T : one wave per output ----------
__global__ __launch_bounds__(256) void ada_k(const float* __restrict__ cond,
                                             const float* __restrict__ nw,
                                             float* __restrict__ ada) {
  int j = blockIdx.x * 4 + (threadIdx.x >> 6);
  int b = blockIdx.y;
  int l = threadIdx.x & 63;
  const float* cp = cond + b * 1024;
  const float* wp = nw + (size_t)j * 1024;
  float s = 0.f;
  for (int c = l; c < 1024; c += 64) s += cp[c] * wp[c];
  s = wsum(s);
  if (l == 0) ada[b * 1024 + j] = 1.f + s;
}

// ---------- RMSNorm(ada) + act_quant -> bf16 activations ----------
__global__ __launch_bounds__(256) void rmsq_k(const float* __restrict__ x,
                                              const float* __restrict__ ada,
                                              unsigned short* __restrict__ Aq) {
  int row = blockIdx.x;          // b*2048 + t
  int b = row >> 11;
  const float* xr = x + (size_t)row * 1024;
  const float* ar = ada + b * 1024;
  float v[4]; float ss = 0.f;
  for (int i = 0; i < 4; i++) { v[i] = xr[threadIdx.x + i * 256]; ss += v[i] * v[i]; }
  ss = wsum(ss);
  __shared__ float sh[4], sh2[4];
  if ((threadIdx.x & 63) == 0) sh[threadIdx.x >> 6] = ss;
  __syncthreads();
  float inv = rsqrtf((sh[0] + sh[1] + sh[2] + sh[3]) * (1.f / 1024.f) + 1e-6f);
  float xn[4]; float mx = 0.f;
  for (int i = 0; i < 4; i++) {
    xn[i] = v[i] * ar[threadIdx.x + i * 256] * inv;
    mx = fmaxf(mx, fabsf(xn[i]));
  }
  mx = wmaxr(mx);
  if ((threadIdx.x & 63) == 0) sh2[threadIdx.x >> 6] = mx;
  __syncthreads();
  float rmax = fmaxf(fmaxf(sh2[0], sh2[1]), fmaxf(sh2[2], sh2[3]));
  float s = 127.f / fmaxf(rmax, 1e-5f);
  float is = 1.f / s;
  unsigned short* dst = Aq + (size_t)row * 1024;
  for (int i = 0; i < 4; i++) {
    float q = fminf(fmaxf(rintf(xn[i] * s), -128.f), 127.f) * is;
    dst[threadIdx.x + i * 256] = f2bf(q);
  }
}

// ---------- act_quant of attention output ----------
__global__ __launch_bounds__(256) void oquant_k(const float* __restrict__ of,
                                                unsigned short* __restrict__ Oq) {
  int row = blockIdx.x;
  const float* xr = of + (size_t)row * 1024;
  float v[4]; float mx = 0.f;
  for (int i = 0; i < 4; i++) { v[i] = xr[threadIdx.x + i * 256]; mx = fmaxf(mx, fabsf(v[i])); }
  mx = wmaxr(mx);
  __shared__ float sh[4];
  if ((threadIdx.x & 63) == 0) sh[threadIdx.x >> 6] = mx;
  __syncthreads();
  float rmax = fmaxf(fmaxf(sh[0], sh[1]), fmaxf(sh[2], sh[3]));
  float s = 127.f / fmaxf(rmax, 1e-5f);
  float is = 1.f / s;
  unsigned short* dst = Oq + (size_t)row * 1024;
  for (int i = 0; i < 4; i++)
    dst[threadIdx.x + i * 256] = f2bf(fminf(fmaxf(rintf(v[i] * s), -128.f), 127.f) * is);
}

// ---------- C[M][N] = A[M][K] * B[N][K]^T, bf16 MFMA, 64x64 tile ----------
__global__ __launch_bounds__(256) void gemm_bt(const unsigned short* __restrict__ A,
                                               const unsigned short* __restrict__ Bw,
                                               int N, int K, int mode,
                                               const float* __restrict__ skip,
                                               float* __restrict__ outF,
                                               unsigned short* __restrict__ outB) {
  __shared__ unsigned short As[64][40];
  __shared__ unsigned short Bs[64][40];
  int tm = blockIdx.x * 64, tn = blockIdx.y * 64;
  int tid = threadIdx.x;
  int l = tid & 63, w = tid >> 6;
  int q = l & 15, g = l >> 4;
  f32x4 acc[4];
  f32x4 zero = {0.f, 0.f, 0.f, 0.f};
  for (int i = 0; i < 4; i++) acc[i] = zero;
  int sr = tid >> 2, sc = (tid & 3) * 8;
  for (int k0 = 0; k0 < K; k0 += 32) {
    *(bf16x8*)&As[sr][sc] = *(const bf16x8*)(A + (size_t)(tm + sr) * K + k0 + sc);
    *(bf16x8*)&Bs[sr][sc] = *(const bf16x8*)(Bw + (size_t)(tn + sr) * K + k0 + sc);
    __syncthreads();
    bf16x8 af = *(const bf16x8*)&As[w * 16 + q][g * 8];
    for (int nb = 0; nb < 4; nb++) {
      bf16x8 bfg = *(const bf16x8*)&Bs[nb * 16 + q][g * 8];
      acc[nb] = __builtin_amdgcn_mfma_f32_16x16x32_bf16(af, bfg, acc[nb], 0, 0, 0);
    }
    __syncthreads();
  }
  for (int nb = 0; nb < 4; nb++) {
    int col = tn + nb * 16 + q;
    for (int r = 0; r < 4; r++) {
      int row = tm + w * 16 + g * 4 + r;
      float vv = acc[nb][r];
      if (mode == 0) outB[(size_t)row * N + col] = f2bf(vv);
      else { size_t idx = (size_t)row * N + col; outF[idx] = vv + skip[idx]; }
    }
  }
}

// ---------- qk-norm + RoPE: one wave per (b,t,h), lane = head-dim ----------
__global__ __launch_bounds__(256) void rope_k(const unsigned short* __restrict__ qkv,
                                              const float* __restrict__ pos,
                                              const float* __restrict__ scale,
                                              const float* __restrict__ freqs,
                                              unsigned short* __restrict__ Qo,
                                              unsigned short* __restrict__ Ko) {
  int tid = threadIdx.x;
  int w = tid >> 6, l = tid & 63;
  int gw = blockIdx.x * 4 + w;            // b*32768 + t*16 + h
  int h = gw & 15, t = (gw >> 4) & 2047, b = gw >> 15;
  const unsigned short* base = qkv + ((size_t)(b * 2048 + t)) * 3072 + h * 64 + l;
  float qv = bf2f(base[0]);
  float kv = bf2f(base[1024]);
  float sq = qv * qv, sk = kv * kv;
  for (int o = 32; o; o >>= 1) { sq += __shfl_xor(sq, o); sk += __shfl_xor(sk, o); }
  float ssc = sqrtf(scale[h]);
  float fq = ssc * rsqrtf(sq + 1e-6f);
  float fk = ssc * rsqrtf(sk + 1e-6f);
  float qn = qv * fq, kn = kv * fk;
  int e = l;
  int idx24 = (e < 24) ? e : e - 24;
  int partner = (e < 24) ? e + 24 : ((e < 48) ? e - 24 : e);
  float qo = __shfl(qn, partner), ko = __shfl(kn, partner);
  float qr = qn, kr = kn;
  if (e < 48) {
    int a = idx24 >> 3, f = idx24 & 7;
    float th = pos[((size_t)(b * 2048 + t)) * 3 + a] * freqs[h * 8 + f];
    float sn, cs; sincosf(th, &sn, &cs);
    if (e < 24) { qr = qn * cs - qo * sn; kr = kn * cs - ko * sn; }
    else        { qr = qn * cs + qo * sn; kr = kn * cs + ko * sn; }
  }
  size_t oi = ((size_t)((b * 16 + h) * 2048 + t)) * 64 + e;
  Qo[oi] = f2bf(qr);
  Ko[oi] = f2bf(kr);
}

// ---------- V transpose: VT[b][h][e][t] ----------
__global__ __launch_bounds__(256) void vtrans_k(const unsigned short* __restrict__ qkv,
                                                unsigned short* __restrict__ VT) {
  __shared__ unsigned short tile[64][72];
  int tt = blockIdx.x, bh = blockIdx.y;
  int b = bh >> 4, h = bh & 15;
  int tid = threadIdx.x;
  for (int ro = 0; ro < 2; ro++) {
    int r = ro * 32 + (tid >> 3);
    int c = (tid & 7) * 8;
    *(bf16x8*)&tile[r][c] =
        *(const bf16x8*)(qkv + ((size_t)(b * 2048 + tt * 64 + r)) * 3072 + 2048 + h * 64 + c);
  }
  __syncthreads();
  int e = tid >> 2;
  int tc = (tid & 3) * 16;
  bf16x8 o0, o1;
  for (int i = 0; i < 8; i++) { o0[i] = (short)tile[tc + i][e]; o1[i] = (short)tile[tc + 8 + i][e]; }
  unsigned short* dst = VT + ((size_t)(bh * 64 + e)) * 2048 + tt * 64 + tc;
  *(bf16x8*)dst = o0;
  *(bf16x8*)(dst + 8) = o1;
}

// ---------- flash attention v2: block stages K/V in LDS, 32 Q-rows/wave ----------
// grid: 512 blocks = 32 bh * 16 q-groups; block = 256 thr = 4 waves; wave = 32 Q-rows
__global__ __launch_bounds__(256) void attn_k(const unsigned short* __restrict__ Q,
                                              const unsigned short* __restrict__ K,
                                              const unsigned short* __restrict__ VT,
                                              float* __restrict__ O) {
  __shared__ unsigned short Ks[64][72];      // [ktok][e], +8 pad
  __shared__ unsigned short Vs[64][72];      // [e][ktok], +8 pad
  __shared__ unsigned short Ps[4][32][72];   // per-wave P^T [qrow][ktok]
  int tid = threadIdx.x;
  int w = tid >> 6, l = tid & 63;
  int q = l & 15, g = l >> 4;
  int bh = blockIdx.x >> 4;
  int qg = blockIdx.x & 15;
  int qrow0 = qg * 128 + w * 32;
  const unsigned short* Kb = K + (size_t)bh * 2048 * 64;
  const unsigned short* Vb = VT + (size_t)bh * 64 * 2048;
  // Q fragments for the 2 q-subtiles (B-operand: col=lane&15=q, k=g*8..)
  bf16x8 qa[2][2];
  for (int j = 0; j < 2; j++) {
    const unsigned short* Qp = Q + ((size_t)bh * 2048 + qrow0 + j * 16 + q) * 64 + g * 8;
    qa[j][0] = *(const bf16x8*)Qp;
    qa[j][1] = *(const bf16x8*)(Qp + 32);
  }
  // staging slots: 2 x bf16x8 per thread (512 slots of 16B per 8KB tile)
  int s0r = tid >> 3, s1r = (tid + 256) >> 3;
  int s0c = (tid & 7) * 8, s1c = s0c;
  const unsigned short* Kg0 = Kb + (size_t)s0r * 64 + s0c;
  const unsigned short* Kg1 = Kb + (size_t)s1r * 64 + s1c;
  const unsigned short* Vg0 = Vb + (size_t)s0r * 2048 + s0c;
  const unsigned short* Vg1 = Vb + (size_t)s1r * 2048 + s1c;

  f32x4 zero = {0.f, 0.f, 0.f, 0.f};
  f32x4 acc[2][4];
  for (int j = 0; j < 2; j++)
    for (int e = 0; e < 4; e++) acc[j][e] = zero;
  float m[2] = {-INFINITY, -INFINITY};
  float sum[2] = {0.f, 0.f};

  // prologue: stage tile 0
  bf16x8 kp0 = *(const bf16x8*)Kg0;
  bf16x8 kp1 = *(const bf16x8*)Kg1;
  bf16x8 vp0 = *(const bf16x8*)Vg0;
  bf16x8 vp1 = *(const bf16x8*)Vg1;
  *(bf16x8*)&Ks[s0r][s0c] = kp0;
  *(bf16x8*)&Ks[s1r][s1c] = kp1;
  *(bf16x8*)&Vs[s0r][s0c] = vp0;
  *(bf16x8*)&Vs[s1r][s1c] = vp1;
  __syncthreads();

  for (int kt = 0; kt < 2048; kt += 64) {
    bool more = (kt + 64) < 2048;
    if (more) {  // async prefetch next tile into regs (T14: issue early)
      kp0 = *(const bf16x8*)(Kg0 + (size_t)(kt + 64) * 64);
      kp1 = *(const bf16x8*)(Kg1 + (size_t)(kt + 64) * 64);
      vp0 = *(const bf16x8*)(Vg0 + kt + 64);
      vp1 = *(const bf16x8*)(Vg1 + kt + 64);
    }
    // ---- QK^T: S^T[ktok][q] for both q-subtiles ----
    f32x4 s[2][4];
    for (int sub = 0; sub < 4; sub++) {
      bf16x8 ka0 = *(const bf16x8*)&Ks[sub * 16 + q][g * 8];
      bf16x8 ka1 = *(const bf16x8*)&Ks[sub * 16 + q][32 + g * 8];
      s[0][sub] = __builtin_amdgcn_mfma_f32_16x16x32_bf16(ka0, qa[0][0], zero, 0, 0, 0);
      s[0][sub] = __builtin_amdgcn_mfma_f32_16x16x32_bf16(ka1, qa[0][1], s[0][sub], 0, 0, 0);
      s[1][sub] = __builtin_amdgcn_mfma_f32_16x16x32_bf16(ka0, qa[1][0], zero, 0, 0, 0);
      s[1][sub] = __builtin_amdgcn_mfma_f32_16x16x32_bf16(ka1, qa[1][1], s[1][sub], 0, 0, 0);
    }
    // ---- online softmax with defer-max (THR=8) ----
    for (int j = 0; j < 2; j++) {
      float tm = -INFINITY;
      for (int sub = 0; sub < 4; sub++)
        tm = fmaxf(tm, fmaxf(fmaxf(s[j][sub][0], s[j][sub][1]),
                             fmaxf(s[j][sub][2], s[j][sub][3])));
      tm = fmaxf(tm, __shfl_xor(tm, 16));
      tm = fmaxf(tm, __shfl_xor(tm, 32));
      if (!__all(tm - m[j] <= 8.f)) {   // rescale only when max grew
        float mn = fmaxf(m[j], tm);
        float alpha = __expf(m[j] - mn);
        sum[j] *= alpha;
        for (int e = 0; e < 4; e++)
          for (int r = 0; r < 4; r++) acc[j][e][r] *= alpha;
        m[j] = mn;
      }
      float ts = 0.f;
      for (int sub = 0; sub < 4; sub++) {
        bf16x4 u;
        for (int r = 0; r < 4; r++) {
          float p = __expf(s[j][sub][r] - m[j]);
          ts += p;
          u[r] = (short)f2bf(p);
        }
        *(bf16x4*)&Ps[w][j * 16 + q][sub * 16 + g * 4] = u;
      }
      ts += __shfl_xor(ts, 16);
      ts += __shfl_xor(ts, 32);
      sum[j] += ts;
    }
    __builtin_amdgcn_sched_barrier(0);   // keep Ps writes before reads
    // ---- PV: O^T += V^T . P^T ----
    bf16x8 pb[2][2];
    for (int j = 0; j < 2; j++)
      for (int ks = 0; ks < 2; ks++)
        pb[j][ks] = *(const bf16x8*)&Ps[w][j * 16 + q][ks * 32 + g * 8];
    for (int eb = 0; eb < 4; eb++) {
      bf16x8 va0 = *(const bf16x8*)&Vs[eb * 16 + q][g * 8];
      bf16x8 va1 = *(const bf16x8*)&Vs[eb * 16 + q][32 + g * 8];
      acc[0][eb] = __builtin_amdgcn_mfma_f32_16x16x32_bf16(va0, pb[0][0], acc[0][eb], 0, 0, 0);
      acc[0][eb] = __builtin_amdgcn_mfma_f32_16x16x32_bf16(va1, pb[0][1], acc[0][eb], 0, 0, 0);
      acc[1][eb] = __builtin_amdgcn_mfma_f32_16x16x32_bf16(va0, pb[1][0], acc[1][eb], 0, 0, 0);
      acc[1][eb] = __builtin_amdgcn_mfma_f32_16x16x32_bf16(va1, pb[1][1], acc[1][eb], 0, 0, 0);
    }
    // ---- swap tile: write prefetched regs after all waves done reading ----
    __syncthreads();
    if (more) {
      *(bf16x8*)&Ks[s0r][s0c] = kp0;
      *(bf16x8*)&Ks[s1r][s1c] = kp1;
      *(bf16x8*)&Vs[s0r][s0c] = vp0;
      *(bf16x8*)&Vs[s1r][s1c] = vp1;
    }
    __syncthreads();
  }
  // epilogue
  int b = bh >> 4, h = bh & 15;
  for (int j = 0; j < 2; j++) {
    float is = 1.f / sum[j];
    float* Op = O + ((size_t)(b * 2048 + qrow0 + j * 16 + q)) * 1024 + h * 64 + g * 4;
    for (int eb = 0; eb < 4; eb++) {
      f32x4 vvv;
      for (int r = 0; r < 4; r++) vvv[r] = acc[j][eb][r] * is;
      *(f32x4*)(Op + eb * 16) = vvv;
    }
  }
}

extern "C" void kernel_launch(void* const* d_in, const int* in_sizes, int n_in,
                              void* d_out, int out_size, void* d_ws, size_t ws_size,
                              hipStream_t stream) {
  const float* x      = (const float*)d_in[0];
  const float* pos    = (const float*)d_in[1];
  const float* cond   = (const float*)d_in[2];
  const float* norm_w = (const float*)d_in[3];
  const float* qkv_w  = (const float*)d_in[4];
  const float* out_w  = (const float*)d_in[5];
  const float* scale  = (const float*)d_in[6];
  const float* freqs  = (const float*)d_in[7];
  float* out = (float*)d_out;
  char* ws = (char*)d_ws;

  const size_t o_ada    = 0;
  const size_t o_rowsum = 8192;
  const size_t o_scales = 24576;
  const size_t o_Wq     = 24832;
  const size_t o_Wo     = o_Wq + 3072ull*1024*2;
  const size_t o_Aq     = o_Wo + 1024ull*1024*2;
  const size_t o_qkv    = o_Aq + 4096ull*1024*2;
  const size_t o_K      = o_qkv + 4096ull*3072*2;
  const size_t o_VT     = o_K + 2ull*16*2048*64*2;

  float* ada            = (float*)(ws + o_ada);
  float* rowsum         = (float*)(ws + o_rowsum);
  float* scales         = (float*)(ws + o_scales);
  unsigned short* Wq    = (unsigned short*)(ws + o_Wq);
  unsigned short* Wo    = (unsigned short*)(ws + o_Wo);
  unsigned short* Aq    = (unsigned short*)(ws + o_Aq);
  unsigned short* Qb    = Aq;
  unsigned short* qkv   = (unsigned short*)(ws + o_qkv);
  float* of             = (float*)(ws + o_qkv);
  unsigned short* Kb    = (unsigned short*)(ws + o_K);
  unsigned short* Oq    = Kb;
  unsigned short* VT    = (unsigned short*)(ws + o_VT);

  wred_k<<<4096, 256, 0, stream>>>(qkv_w, out_w, rowsum);
  finalize_k<<<1, 256, 0, stream>>>(rowsum, scales);
  wquant_k<<<4096, 256, 0, stream>>>(qkv_w, out_w, scales, Wq, Wo);
  ada_k<<<dim3(256, 2), 256, 0, stream>>>(cond, norm_w, ada);
  rmsq_k<<<4096, 256, 0, stream>>>(x, ada, Aq);
  gemm_bt<<<dim3(64, 48), 256, 0, stream>>>(Aq, Wq, 3072, 1024, 0, nullptr, nullptr, qkv);
  rope_k<<<16384, 256, 0, stream>>>(qkv, pos, scale, freqs, Qb, Kb);
  vtrans_k<<<dim3(32, 32), 256, 0, stream>>>(qkv, VT);
  attn_k<<<512, 256, 0, stream>>>(Qb, Kb, VT, of);
  oquant_k<<<4096, 256, 0, stream>>>(of, Oq);
  gemm_bt<<<dim3(64, 16), 256, 0, stream>>>(Oq, Wo, 1024, 1024, 1, x, out, nullptr);
}